// Round 1
// baseline (326.099 us; speedup 1.0000x reference)
//
#include <hip/hip_runtime.h>

// VQ codebook assignment: out[q][:] = codebook[argmin_k ||z[q]-cb[k]||^2]
// argmin_k (|z|^2 - 2 z.c + |c|^2) == argmin_k (csq[k] - 2 z.c_k)  (drop z^2)
// fp32 register-tiled distance GEMM + fused argmin + gather. fp64 chunk
// accumulation to keep distance error (~5e-5) far below the top-2 gap.

#define NB 16
#define NT 2048
#define ND 256
#define NK 1024
#define NQ (NB * NT)   // 32768 queries

__global__ __launch_bounds__(256, 2)
void vq_argmin_gather(const float* __restrict__ z,
                      const float* __restrict__ cb,
                      float* __restrict__ out)
{
    // LDS: 65536 + 8192 + 4096 + 256 = 78080 B -> 2 blocks/CU (160 KiB LDS)
    __shared__ float z_t[ND][64];    // transposed z tile, col-swizzled
    __shared__ float cb_t[32][64];   // transposed cb d-chunk, col-swizzled
    __shared__ float csq[NK];        // |c_k|^2 (f64-accurate, stored f32)
    __shared__ int   idx_lds[64];

    const int tid = threadIdx.x;
    const int tx  = tid & 15;        // code group   (4 codes each)
    const int ty  = tid >> 4;        // query group  (4 queries each)
    const int q0  = blockIdx.x * 64;

    // ---- stage z tile (64 q x 256 d) transposed; swizzle s(d)=4*((d>>2)&7)
    {
        const int r  = tid >> 6;         // 0..3
        const int c4 = (tid & 63) * 4;   // d base
        #pragma unroll
        for (int it = 0; it < 16; ++it) {
            const int q = it * 4 + r;
            const float4 v = *reinterpret_cast<const float4*>(
                &z[(size_t)(q0 + q) * ND + c4]);
            const float vv[4] = {v.x, v.y, v.z, v.w};
            #pragma unroll
            for (int j = 0; j < 4; ++j) {
                const int d = c4 + j;
                const int s = 4 * ((d >> 2) & 7);
                z_t[d][q ^ s] = vv[j];
            }
        }
    }

    // ---- csq[k] = sum_d cb[k][d]^2 (f64 accum, 16-lane groups, 1 row/group)
    {
        const int lane16 = tid & 15;
        const int rgrp   = tid >> 4;     // 0..15
        #pragma unroll 4
        for (int it = 0; it < 64; ++it) {
            const int k = it * 16 + rgrp;
            double ssum = 0.0;
            #pragma unroll
            for (int h = 0; h < 4; ++h) {
                const float4 v = *reinterpret_cast<const float4*>(
                    &cb[(size_t)k * ND + lane16 * 16 + h * 4]);
                ssum += (double)v.x * v.x + (double)v.y * v.y
                      + (double)v.z * v.z + (double)v.w * v.w;
            }
            #pragma unroll
            for (int m = 8; m >= 1; m >>= 1)
                ssum += __shfl_xor(ssum, m);
            if (lane16 == 0) csq[k] = (float)ssum;
        }
    }

    double bestd[4];
    int    besti[4];
    #pragma unroll
    for (int i = 0; i < 4; ++i) { bestd[i] = 1e300; besti[i] = 0; }

    for (int kt = 0; kt < 16; ++kt) {
        double acc[4][4];
        #pragma unroll
        for (int i = 0; i < 4; ++i)
            #pragma unroll
            for (int j = 0; j < 4; ++j) acc[i][j] = 0.0;

        for (int dc = 0; dc < 8; ++dc) {
            __syncthreads();   // protect cb_t (and first-iter z_t/csq) reuse
            // stage cb chunk: codes kt*64..+63, d = dc*32..+31, transposed
            {
                const int kk = tid >> 3;        // 0..31
                const int dd = (tid & 7) * 4;   // 0,4,..,28
                #pragma unroll
                for (int h = 0; h < 2; ++h) {
                    const int k = kk + h * 32;
                    const float4 v = *reinterpret_cast<const float4*>(
                        &cb[(size_t)(kt * 64 + k) * ND + dc * 32 + dd]);
                    const float vv[4] = {v.x, v.y, v.z, v.w};
                    #pragma unroll
                    for (int j = 0; j < 4; ++j) {
                        const int d = dd + j;
                        const int s = 4 * ((d >> 2) & 7);
                        cb_t[d][k ^ s] = vv[j];
                    }
                }
            }
            __syncthreads();

            float cr[4][4];
            #pragma unroll
            for (int i = 0; i < 4; ++i)
                #pragma unroll
                for (int j = 0; j < 4; ++j) cr[i][j] = 0.0f;

            #pragma unroll 8
            for (int d = 0; d < 32; ++d) {
                const int s  = 4 * ((d >> 2) & 7);
                const int dg = dc * 32 + d;      // (dg>>2)&7 == (d>>2)&7
                const float4 zv4 = *reinterpret_cast<const float4*>(
                    &z_t[dg][(4 * ty) ^ s]);
                const float4 cv4 = *reinterpret_cast<const float4*>(
                    &cb_t[d][(4 * tx) ^ s]);
                const float zv[4] = {zv4.x, zv4.y, zv4.z, zv4.w};
                const float cv[4] = {cv4.x, cv4.y, cv4.z, cv4.w};
                #pragma unroll
                for (int i = 0; i < 4; ++i)
                    #pragma unroll
                    for (int j = 0; j < 4; ++j)
                        cr[i][j] = fmaf(zv[i], cv[j], cr[i][j]);
            }
            #pragma unroll
            for (int i = 0; i < 4; ++i)
                #pragma unroll
                for (int j = 0; j < 4; ++j)
                    acc[i][j] += (double)cr[i][j];
        }

        // fold this k-tile into the running argmin (ascending k, strict <)
        #pragma unroll
        for (int j = 0; j < 4; ++j) {
            const int k = kt * 64 + tx * 4 + j;
            const double cs = (double)csq[k];
            #pragma unroll
            for (int i = 0; i < 4; ++i) {
                const double dist = cs - 2.0 * acc[i][j];
                if (dist < bestd[i]) { bestd[i] = dist; besti[i] = k; }
            }
        }
    }

    // ---- reduce (dist, idx) across the 16 tx lanes; lowest idx on ties
    #pragma unroll
    for (int i = 0; i < 4; ++i) {
        double bd = bestd[i];
        int    bi = besti[i];
        #pragma unroll
        for (int m = 8; m >= 1; m >>= 1) {
            const double od = __shfl_xor(bd, m);
            const int    oi = __shfl_xor(bi, m);
            if (od < bd || (od == bd && oi < bi)) { bd = od; bi = oi; }
        }
        if (tx == 0) idx_lds[ty * 4 + i] = bi;
    }
    __syncthreads();

    // ---- gather: out[q][:] = cb[idx[q]][:]
    {
        const int r = tid >> 6;          // 0..3
        const int c = (tid & 63) * 4;
        #pragma unroll
        for (int it = 0; it < 16; ++it) {
            const int q = it * 4 + r;
            const int k = idx_lds[q];
            const float4 v = *reinterpret_cast<const float4*>(
                &cb[(size_t)k * ND + c]);
            *reinterpret_cast<float4*>(&out[(size_t)(q0 + q) * ND + c]) = v;
        }
    }
}

extern "C" void kernel_launch(void* const* d_in, const int* in_sizes, int n_in,
                              void* d_out, int out_size, void* d_ws, size_t ws_size,
                              hipStream_t stream)
{
    const float* z   = (const float*)d_in[0];   // [B,T,D] fp32
    const float* cbk = (const float*)d_in[1];   // [K,D]  fp32
    float* out = (float*)d_out;                 // [B,T,D] fp32

    dim3 grid(NQ / 64);
    dim3 block(256);
    vq_argmin_gather<<<grid, block, 0, stream>>>(z, cbk, out);
}

// Round 3
// 176.235 us; speedup vs baseline: 1.8504x; 1.8504x over previous
//
#include <hip/hip_runtime.h>
#include <stdint.h>

// VQ codebook assignment via split-precision bf16 MFMA:
//   argmin_k ||z-c_k||^2 == argmin_k (csq[k] - 2 z.c_k)
//   z.c ~= z_hi.c_hi + z_lo.c_hi + z_hi.c_lo   (bf16 hi/lo split, K_eff=768)
// Per-query top-2 margin tracked; margin < TAU queries re-solved in fp64 by a
// fixup kernel (zero-flip safety net vs the np reference).
// Fallback: if ws_size < needed, run the round-1 verified fp32 VALU kernel.

#define NQ 32768
#define ND 256
#define NK 1024
#define TAU 0.0078125f   // 2^-7, ~40 sigma of bf16-split distance error

typedef short bf16x8 __attribute__((ext_vector_type(8)));
typedef float f32x4  __attribute__((ext_vector_type(4)));

// ws layout (bytes); total ~1.19 MB
#define WS_CBW 0                         // ushort cbw[8][1024][64] pre-swizzled
#define WS_CSQ (8 * 1024 * 64 * 2)       // double csq[1024]
#define WS_CNT (WS_CSQ + 1024 * 8)       // int count
#define WS_LST (WS_CNT + 16)             // int list[32768]
#define WS_NEEDED (WS_LST + NQ * 4)

__device__ __forceinline__ ushort bf_trunc(float x) {
    return (ushort)(__builtin_bit_cast(uint32_t, x) >> 16);
}
__device__ __forceinline__ float bf_back(ushort h) {
    return __builtin_bit_cast(float, ((uint32_t)h) << 16);
}

// ---------------------------------------------------------------- prep ----
// One block per code: convert cb row to (hi,lo) bf16 into cbw with the LDS
// swizzle pre-applied to the GLOBAL layout (so global_load_lds stays linear),
// and compute csq in fp64. Phys chunks: p<4 = c_hi d-chunk p, p>=4 = c_lo.
__global__ __launch_bounds__(64)
void vq_prep(const float* __restrict__ cb, uint8_t* __restrict__ ws)
{
    ushort* cbw = (ushort*)(ws + WS_CBW);
    double* csq = (double*)(ws + WS_CSQ);
    int*    cnt = (int*)(ws + WS_CNT);

    const int code = blockIdx.x;
    const int lane = threadIdx.x;          // 0..63
    if (code == 0 && lane == 0) *cnt = 0;  // re-zero every launch (determinism)

    const int d0 = lane * 4;
    const float4 v = *reinterpret_cast<const float4*>(&cb[(size_t)code * ND + d0]);
    const float xs[4] = {v.x, v.y, v.z, v.w};

    ushort hi[4], lo[4];
    double ss = 0.0;
    #pragma unroll
    for (int j = 0; j < 4; ++j) {
        hi[j] = bf_trunc(xs[j]);
        lo[j] = bf_trunc(xs[j] - bf_back(hi[j]));
        ss += (double)xs[j] * (double)xs[j];
    }

    const int p  = d0 >> 6;          // hi chunk 0..3
    const int k  = d0 & 63;
    const int u  = k >> 3;           // 16B unit within 64-k chunk row
    const int r  = k & 7;            // 0 or 4
    const int us = (u ^ (code & 7)); // pre-swizzle (inverse == same involution)

    ushort4 h4; h4.x = hi[0]; h4.y = hi[1]; h4.z = hi[2]; h4.w = hi[3];
    ushort4 l4; l4.x = lo[0]; l4.y = lo[1]; l4.z = lo[2]; l4.w = lo[3];
    *reinterpret_cast<ushort4*>(
        &cbw[((size_t)p * NK + code) * 64 + (us << 3) + r]) = h4;
    *reinterpret_cast<ushort4*>(
        &cbw[((size_t)(p + 4) * NK + code) * 64 + (us << 3) + r]) = l4;

    #pragma unroll
    for (int m = 1; m < 64; m <<= 1) ss += __shfl_xor(ss, m);
    if (lane == 0) csq[code] = ss;
}

// ---------------------------------------------------------------- main ----
__global__ __launch_bounds__(256, 1)
void vq_main(const float* __restrict__ z, const float* __restrict__ cb,
             uint8_t* __restrict__ ws, float* __restrict__ out)
{
    __shared__ ushort zt[64][512];        // z hi(0:256)|lo(256:512), swizzled
    __shared__ ushort cbt[2][256][64];    // cb chunk double buffer (linear copy)
    __shared__ float  csq_l[NK];
    __shared__ float  wb1[4][64], wb2[4][64];
    __shared__ int    wbi[4][64];
    __shared__ int    qidx[64];

    const ushort* cbw  = (const ushort*)(ws + WS_CBW);
    const double* csqd = (const double*)(ws + WS_CSQ);
    int* cnt = (int*)(ws + WS_CNT);
    int* lst = (int*)(ws + WS_LST);

    const int tid  = threadIdx.x;
    const int lane = tid & 63;
    const int w    = tid >> 6;            // wave 0..3
    const int q0   = blockIdx.x * 64;

    // --- issue first cb chunk stage (nt=0, pc=0 -> phys chunk 0), async
    {
        const ushort* src = cbw;          // chunk 0, code-tile 0
        #pragma unroll
        for (int it = 0; it < 8; ++it) {
            __builtin_amdgcn_global_load_lds(
                (const __attribute__((address_space(1))) void*)(src + tid * 8 + it * 2048),
                (__attribute__((address_space(3))) void*)(&cbt[0][0][0] + tid * 8 + it * 2048),
                16, 0, 0);
        }
    }

    // --- stage z tile: convert 64x256 fp32 -> hi/lo bf16, swizzled 16B units
    {
        const int rr = tid >> 6;          // 0..3
        const int c4 = (tid & 63) * 4;    // d base
        const int uh = c4 >> 3;
        const int ul = (256 + c4) >> 3;
        #pragma unroll
        for (int it = 0; it < 16; ++it) {
            const int q = it * 4 + rr;
            const float4 v = *reinterpret_cast<const float4*>(
                &z[(size_t)(q0 + q) * ND + c4]);
            const float xs[4] = {v.x, v.y, v.z, v.w};
            ushort4 h4, l4;
            ushort* hp = &h4.x; ushort* lp = &l4.x;
            #pragma unroll
            for (int j = 0; j < 4; ++j) {
                const ushort h = bf_trunc(xs[j]);
                hp[j] = h;
                lp[j] = bf_trunc(xs[j] - bf_back(h));
            }
            const int sw = q & 7;
            *reinterpret_cast<ushort4*>(&zt[q][((uh ^ sw) << 3) + (c4 & 7)]) = h4;
            *reinterpret_cast<ushort4*>(&zt[q][((ul ^ sw) << 3) + (c4 & 7)]) = l4;
        }
    }
    #pragma unroll
    for (int i = 0; i < 4; ++i) csq_l[tid * 4 + i] = (float)csqd[tid * 4 + i];

    asm volatile("s_waitcnt vmcnt(0)" ::: "memory");
    __syncthreads();

    float b1[16], b2[16]; int bidx[16];
    #pragma unroll
    for (int s = 0; s < 16; ++s) { b1[s] = 3.0e38f; b2[s] = 3.0e38f; bidx[s] = 0; }

    const int kq = (lane >> 4) * 8;       // k-octet within K=32 step

#define STEP_B(KL)                                                             \
    bf16x8 bfr[4];                                                             \
    {                                                                          \
        _Pragma("unroll")                                                      \
        for (int ni = 0; ni < 4; ++ni) {                                       \
            const int c  = w * 64 + ni * 16 + (lane & 15);                     \
            const int ub = ((KL) + kq) >> 3;                                   \
            bfr[ni] = *reinterpret_cast<const bf16x8*>(                        \
                &cbt[buf][c][(ub ^ (c & 7)) << 3]);                            \
        }                                                                      \
    }
#define STEP_A_MFMA(ZB)                                                        \
    {                                                                          \
        bf16x8 afr[4];                                                         \
        _Pragma("unroll")                                                      \
        for (int mi = 0; mi < 4; ++mi) {                                       \
            const int q  = mi * 16 + (lane & 15);                              \
            const int uc = ((ZB) + kq) >> 3;                                   \
            afr[mi] = *reinterpret_cast<const bf16x8*>(                        \
                &zt[q][(uc ^ (q & 7)) << 3]);                                  \
        }                                                                      \
        _Pragma("unroll")                                                      \
        for (int mi = 0; mi < 4; ++mi)                                         \
            _Pragma("unroll")                                                  \
            for (int ni = 0; ni < 4; ++ni)                                     \
                acc[mi][ni] = __builtin_amdgcn_mfma_f32_16x16x32_bf16(         \
                    afr[mi], bfr[ni], acc[mi][ni], 0, 0, 0);                   \
    }

    int buf = 0;
    #pragma unroll 1
    for (int nt = 0; nt < 4; ++nt) {
        f32x4 acc[4][4];
        #pragma unroll
        for (int mi = 0; mi < 4; ++mi)
            #pragma unroll
            for (int ni = 0; ni < 4; ++ni)
                acc[mi][ni] = (f32x4){0.f, 0.f, 0.f, 0.f};

        #pragma unroll 1
        for (int pc = 0; pc < 8; ++pc) {
            // prefetch next chunk into buf^1
            if (!(nt == 3 && pc == 7)) {
                const int nnt = (pc == 7) ? nt + 1 : nt;
                const int npc = (pc == 7) ? 0 : pc + 1;
                const ushort* src = cbw + ((size_t)npc * NK + nnt * 256) * 64;
                ushort* dst = &cbt[buf ^ 1][0][0];
                #pragma unroll
                for (int it = 0; it < 8; ++it) {
                    __builtin_amdgcn_global_load_lds(
                        (const __attribute__((address_space(1))) void*)(src + tid * 8 + it * 2048),
                        (__attribute__((address_space(3))) void*)(dst + tid * 8 + it * 2048),
                        16, 0, 0);
                }
            }
            // compute on cbt[buf]
            if (pc < 4) {
                const int zb = pc * 64;           // c_hi chunk: z_hi & z_lo terms
                { STEP_B(0)  STEP_A_MFMA(zb)       STEP_A_MFMA(256 + zb) }
                { STEP_B(32) STEP_A_MFMA(zb + 32)  STEP_A_MFMA(256 + zb + 32) }
            } else {
                const int zb = (pc - 4) * 64;     // c_lo chunk: z_hi term
                { STEP_B(0)  STEP_A_MFMA(zb) }
                { STEP_B(32) STEP_A_MFMA(zb + 32) }
            }
            asm volatile("s_waitcnt vmcnt(0)" ::: "memory");
            __syncthreads();
            buf ^= 1;
        }

        // fold this N-tile into running top-2
        #pragma unroll
        for (int ni = 0; ni < 4; ++ni) {
            const int code = nt * 256 + w * 64 + ni * 16 + (lane & 15);
            const float cs = csq_l[code];
            #pragma unroll
            for (int mi = 0; mi < 4; ++mi)
                #pragma unroll
                for (int r = 0; r < 4; ++r) {
                    const float d = fmaf(-2.0f, acc[mi][ni][r], cs);
                    const int s = mi * 4 + r;
                    if (d < b1[s]) { b2[s] = b1[s]; b1[s] = d; bidx[s] = code; }
                    else if (d < b2[s]) b2[s] = d;
                }
        }
    }

    // --- cross-lane top-2 reduce within each 16-lane column group
    #pragma unroll
    for (int s = 0; s < 16; ++s) {
        float B1 = b1[s], B2 = b2[s]; int BI = bidx[s];
        #pragma unroll
        for (int m = 1; m < 16; m <<= 1) {
            const float o1 = __shfl_xor(B1, m);
            const float o2 = __shfl_xor(B2, m);
            const int   oi = __shfl_xor(BI, m);
            const float n2 = fminf(fmaxf(B1, o1), fminf(B2, o2));
            const bool sel = (o1 < B1) || (o1 == B1 && oi < BI);
            B1 = fminf(B1, o1); BI = sel ? oi : BI; B2 = n2;
        }
        if ((lane & 15) == 0) {
            const int mi = s >> 2, r = s & 3, g = lane >> 4;
            const int q = mi * 16 + g * 4 + r;
            wb1[w][q] = B1; wb2[w][q] = B2; wbi[w][q] = BI;
        }
    }
    __syncthreads();

    // --- combine 4 wave candidates, flag tight margins
    if (tid < 64) {
        float B1 = wb1[0][tid], B2 = wb2[0][tid]; int BI = wbi[0][tid];
        #pragma unroll
        for (int ww = 1; ww < 4; ++ww) {
            const float o1 = wb1[ww][tid], o2 = wb2[ww][tid];
            const int   oi = wbi[ww][tid];
            const float n2 = fminf(fmaxf(B1, o1), fminf(B2, o2));
            const bool sel = (o1 < B1) || (o1 == B1 && oi < BI);
            B1 = fminf(B1, o1); BI = sel ? oi : BI; B2 = n2;
        }
        qidx[tid] = BI;
        if (B2 - B1 < TAU) {
            const int pos = atomicAdd(cnt, 1);
            lst[pos] = q0 + tid;
        }
    }
    __syncthreads();

    // --- gather: out[q][:] = cb[idx[q]][:]
    {
        const int rr = tid >> 6;
        const int c  = (tid & 63) * 4;
        #pragma unroll
        for (int it = 0; it < 16; ++it) {
            const int q = it * 4 + rr;
            const int k = qidx[q];
            *reinterpret_cast<float4*>(&out[(size_t)(q0 + q) * ND + c]) =
                *reinterpret_cast<const float4*>(&cb[(size_t)k * ND + c]);
        }
    }
#undef STEP_B
#undef STEP_A_MFMA
}

// --------------------------------------------------------------- fixup ----
// Exact fp64 re-solve for flagged (tight-margin) queries.
__global__ __launch_bounds__(256, 1)
void vq_fix(const float* __restrict__ z, const float* __restrict__ cb,
            uint8_t* __restrict__ ws, float* __restrict__ out)
{
    __shared__ double zd[ND];
    __shared__ double rb[256];
    __shared__ int    ri[256];

    const int* cnt = (const int*)(ws + WS_CNT);
    const int* lst = (const int*)(ws + WS_LST);
    const int tid = threadIdx.x;
    const int n = *cnt;

    for (int i = blockIdx.x; i < n; i += gridDim.x) {
        const int q = lst[i];
        __syncthreads();
        zd[tid] = (double)z[(size_t)q * ND + tid];
        __syncthreads();

        double best = 1.0e300; int bi = 0;
        #pragma unroll 1
        for (int j = 0; j < 4; ++j) {
            const int k = tid * 4 + j;
            double s = 0.0;
            const float* row = &cb[(size_t)k * ND];
            for (int d = 0; d < ND; ++d) {
                const double df = zd[d] - (double)row[d];
                s = fma(df, df, s);
            }
            if (s < best) { best = s; bi = k; }
        }
        rb[tid] = best; ri[tid] = bi;
        __syncthreads();
        for (int m = 128; m > 0; m >>= 1) {
            if (tid < m) {
                if (rb[tid + m] < rb[tid] ||
                    (rb[tid + m] == rb[tid] && ri[tid + m] < ri[tid])) {
                    rb[tid] = rb[tid + m]; ri[tid] = ri[tid + m];
                }
            }
            __syncthreads();
        }
        const int k = ri[0];
        if (tid < 64) {
            const float4 vv = *reinterpret_cast<const float4*>(
                &cb[(size_t)k * ND + tid * 4]);
            *reinterpret_cast<float4*>(&out[(size_t)q * ND + tid * 4]) = vv;
        }
        __syncthreads();
    }
}

// ------------------------------------------------- fallback (round-1) -----
// Verified-passing fp32 VALU kernel (376 us), used only if ws_size is small.
__global__ __launch_bounds__(256, 2)
void vq_fallback(const float* __restrict__ z, const float* __restrict__ cb,
                 float* __restrict__ out)
{
    __shared__ float z_t[ND][64];
    __shared__ float cb_t[32][64];
    __shared__ float csq[NK];
    __shared__ int   idx_lds[64];

    const int tid = threadIdx.x;
    const int tx  = tid & 15;
    const int ty  = tid >> 4;
    const int q0  = blockIdx.x * 64;

    {
        const int r  = tid >> 6;
        const int c4 = (tid & 63) * 4;
        #pragma unroll
        for (int it = 0; it < 16; ++it) {
            const int q = it * 4 + r;
            const float4 v = *reinterpret_cast<const float4*>(
                &z[(size_t)(q0 + q) * ND + c4]);
            const float vv[4] = {v.x, v.y, v.z, v.w};
            #pragma unroll
            for (int j = 0; j < 4; ++j) {
                const int d = c4 + j;
                const int s = 4 * ((d >> 2) & 7);
                z_t[d][q ^ s] = vv[j];
            }
        }
    }
    {
        const int lane16 = tid & 15;
        const int rgrp   = tid >> 4;
        #pragma unroll 4
        for (int it = 0; it < 64; ++it) {
            const int k = it * 16 + rgrp;
            double ssum = 0.0;
            #pragma unroll
            for (int h = 0; h < 4; ++h) {
                const float4 v = *reinterpret_cast<const float4*>(
                    &cb[(size_t)k * ND + lane16 * 16 + h * 4]);
                ssum += (double)v.x * v.x + (double)v.y * v.y
                      + (double)v.z * v.z + (double)v.w * v.w;
            }
            #pragma unroll
            for (int m = 8; m >= 1; m >>= 1) ssum += __shfl_xor(ssum, m);
            if (lane16 == 0) csq[k] = (float)ssum;
        }
    }

    double bestd[4]; int besti[4];
    #pragma unroll
    for (int i = 0; i < 4; ++i) { bestd[i] = 1e300; besti[i] = 0; }

    for (int kt = 0; kt < 16; ++kt) {
        double acc[4][4];
        #pragma unroll
        for (int i = 0; i < 4; ++i)
            #pragma unroll
            for (int j = 0; j < 4; ++j) acc[i][j] = 0.0;

        for (int dc = 0; dc < 8; ++dc) {
            __syncthreads();
            {
                const int kk = tid >> 3;
                const int dd = (tid & 7) * 4;
                #pragma unroll
                for (int h = 0; h < 2; ++h) {
                    const int k = kk + h * 32;
                    const float4 v = *reinterpret_cast<const float4*>(
                        &cb[(size_t)(kt * 64 + k) * ND + dc * 32 + dd]);
                    const float vv[4] = {v.x, v.y, v.z, v.w};
                    #pragma unroll
                    for (int j = 0; j < 4; ++j) {
                        const int d = dd + j;
                        const int s = 4 * ((d >> 2) & 7);
                        cb_t[d][k ^ s] = vv[j];
                    }
                }
            }
            __syncthreads();

            float cr[4][4];
            #pragma unroll
            for (int i = 0; i < 4; ++i)
                #pragma unroll
                for (int j = 0; j < 4; ++j) cr[i][j] = 0.0f;

            #pragma unroll 8
            for (int d = 0; d < 32; ++d) {
                const int s  = 4 * ((d >> 2) & 7);
                const int dg = dc * 32 + d;
                const float4 zv4 = *reinterpret_cast<const float4*>(
                    &z_t[dg][(4 * ty) ^ s]);
                const float4 cv4 = *reinterpret_cast<const float4*>(
                    &cb_t[d][(4 * tx) ^ s]);
                const float zv[4] = {zv4.x, zv4.y, zv4.z, zv4.w};
                const float cv[4] = {cv4.x, cv4.y, cv4.z, cv4.w};
                #pragma unroll
                for (int i = 0; i < 4; ++i)
                    #pragma unroll
                    for (int j = 0; j < 4; ++j)
                        cr[i][j] = fmaf(zv[i], cv[j], cr[i][j]);
            }
            #pragma unroll
            for (int i = 0; i < 4; ++i)
                #pragma unroll
                for (int j = 0; j < 4; ++j)
                    acc[i][j] += (double)cr[i][j];
        }

        #pragma unroll
        for (int j = 0; j < 4; ++j) {
            const int k = kt * 64 + tx * 4 + j;
            const double cs = (double)csq[k];
            #pragma unroll
            for (int i = 0; i < 4; ++i) {
                const double dist = cs - 2.0 * acc[i][j];
                if (dist < bestd[i]) { bestd[i] = dist; besti[i] = k; }
            }
        }
    }

    #pragma unroll
    for (int i = 0; i < 4; ++i) {
        double bd = bestd[i]; int bi = besti[i];
        #pragma unroll
        for (int m = 8; m >= 1; m >>= 1) {
            const double od = __shfl_xor(bd, m);
            const int    oi = __shfl_xor(bi, m);
            if (od < bd || (od == bd && oi < bi)) { bd = od; bi = oi; }
        }
        if (tx == 0) idx_lds[ty * 4 + i] = bi;
    }
    __syncthreads();

    {
        const int r = tid >> 6;
        const int c = (tid & 63) * 4;
        #pragma unroll
        for (int it = 0; it < 16; ++it) {
            const int q = it * 4 + r;
            const int k = idx_lds[q];
            const float4 v = *reinterpret_cast<const float4*>(
                &cb[(size_t)k * ND + c]);
            *reinterpret_cast<float4*>(&out[(size_t)(q0 + q) * ND + c]) = v;
        }
    }
}

extern "C" void kernel_launch(void* const* d_in, const int* in_sizes, int n_in,
                              void* d_out, int out_size, void* d_ws, size_t ws_size,
                              hipStream_t stream)
{
    const float* z   = (const float*)d_in[0];   // [B,T,D] fp32
    const float* cbk = (const float*)d_in[1];   // [K,D]  fp32
    float* out = (float*)d_out;
    uint8_t* ws = (uint8_t*)d_ws;

    if (ws_size < (size_t)WS_NEEDED) {
        vq_fallback<<<NQ / 64, 256, 0, stream>>>(z, cbk, out);
        return;
    }

    vq_prep<<<NK, 64, 0, stream>>>(cbk, ws);
    vq_main<<<NQ / 64, 256, 0, stream>>>(z, cbk, ws, out);
    vq_fix<<<256, 256, 0, stream>>>(z, cbk, ws, out);
}

// Round 4
// 172.936 us; speedup vs baseline: 1.8857x; 1.0191x over previous
//
#include <hip/hip_runtime.h>
#include <stdint.h>

// VQ codebook assignment via split-precision bf16 MFMA:
//   argmin_k ||z-c_k||^2 == argmin_k (csq[k] - 2 z.c_k)
//   z.c ~= z_hi.c_hi + z_lo.c_hi + z_hi.c_lo   (bf16 hi/lo split, K_eff=768)
// Round-4 structure: 8 waves (2m x 4n), 4-slot LDS ring of 16KB chunks,
// counted vmcnt(4) pipeline depth 3, raw s_barrier (1 per step), setprio
// around MFMA. Tight-margin queries re-solved exactly in fp64 (vq_fix).

#define NQ 32768
#define ND 256
#define NK 1024
#define TAU 0.0078125f   // 2^-7 margin threshold for the exact-fixup path

typedef short bf16x8 __attribute__((ext_vector_type(8)));
typedef float f32x4  __attribute__((ext_vector_type(4)));

// ws layout (bytes); total ~1.19 MB
// cbw: ushort [64 chunks][256 codes][32 k], chunk g = ct*16 + kc
//      kc 0..7 = c_hi k-range [kc*32,+32); kc 8..15 = c_lo k-range [(kc-8)*32,+32)
//      row swizzle: 16B unit u (0..3) stored at u ^ (code&3)
#define WS_CBW 0
#define WS_CSQ (64 * 256 * 32 * 2)       // 1 MB; then double csq[1024]
#define WS_CNT (WS_CSQ + 1024 * 8)
#define WS_LST (WS_CNT + 16)
#define WS_NEEDED (WS_LST + NQ * 4)

__device__ __forceinline__ ushort bf_trunc(float x) {
    return (ushort)(__builtin_bit_cast(uint32_t, x) >> 16);
}
__device__ __forceinline__ float bf_back(ushort h) {
    return __builtin_bit_cast(float, ((uint32_t)h) << 16);
}

// ---------------------------------------------------------------- prep ----
__global__ __launch_bounds__(64)
void vq_prep(const float* __restrict__ cb, uint8_t* __restrict__ ws)
{
    ushort* cbw = (ushort*)(ws + WS_CBW);
    double* csq = (double*)(ws + WS_CSQ);
    int*    cnt = (int*)(ws + WS_CNT);

    const int code = blockIdx.x;
    const int lane = threadIdx.x;          // 0..63
    if (code == 0 && lane == 0) *cnt = 0;  // re-zero every launch (determinism)

    const int d0 = lane * 4;
    const float4 v = *reinterpret_cast<const float4*>(&cb[(size_t)code * ND + d0]);
    const float xs[4] = {v.x, v.y, v.z, v.w};

    ushort4 h4, l4;
    ushort* hp = &h4.x; ushort* lp = &l4.x;
    double ss = 0.0;
    #pragma unroll
    for (int j = 0; j < 4; ++j) {
        const ushort h = bf_trunc(xs[j]);
        hp[j] = h;
        lp[j] = bf_trunc(xs[j] - bf_back(h));
        ss += (double)xs[j] * (double)xs[j];
    }

    const int ct = code >> 8;
    const int c2 = code & 255;
    const int kc = d0 >> 5;              // 0..7
    const int u0 = (d0 >> 3) & 3;        // 16B unit within 64B row
    const int r  = d0 & 7;               // 0 or 4
    const int us = u0 ^ (c2 & 3);        // pre-swizzle (involution)

    *reinterpret_cast<ushort4*>(
        &cbw[((size_t)(ct * 16 + kc) * 256 + c2) * 32 + (us << 3) + r]) = h4;
    *reinterpret_cast<ushort4*>(
        &cbw[((size_t)(ct * 16 + 8 + kc) * 256 + c2) * 32 + (us << 3) + r]) = l4;

    #pragma unroll
    for (int m = 1; m < 64; m <<= 1) ss += __shfl_xor(ss, m);
    if (lane == 0) csq[code] = ss;
}

// ---------------------------------------------------------------- main ----
__global__ __launch_bounds__(512, 1)
void vq_main(const float* __restrict__ z, const float* __restrict__ cb,
             uint8_t* __restrict__ ws, float* __restrict__ out)
{
    __shared__ ushort zt[64][512];        // z hi(0:256)|lo(256:512), swizzled
    __shared__ ushort ring[4][256][32];   // 4 x 16KB chunk ring
    __shared__ float  csq_l[NK];
    __shared__ float  wb1[4][64], wb2[4][64];
    __shared__ int    wbi[4][64];
    __shared__ int    qidx[64];

    const ushort* cbw  = (const ushort*)(ws + WS_CBW);
    const double* csqd = (const double*)(ws + WS_CSQ);
    int* cnt = (int*)(ws + WS_CNT);
    int* lst = (int*)(ws + WS_LST);

    const int tid  = threadIdx.x;
    const int lane = tid & 63;
    const int w    = tid >> 6;            // wave 0..7
    const int wy   = w >> 2;              // q-half   (32 rows)
    const int wx   = w & 3;               // code-quarter (64 codes of 256)
    const int q0   = blockIdx.x * 64;

#define ISSUE(G, SLOT)                                                          \
    {                                                                           \
        const ushort* s_ = cbw + (size_t)(G) * 8192;                            \
        ushort* d_ = &ring[(SLOT)][0][0];                                       \
        __builtin_amdgcn_global_load_lds(                                       \
            (const __attribute__((address_space(1))) void*)(s_ + tid * 8),      \
            (__attribute__((address_space(3))) void*)(d_ + tid * 8), 16, 0, 0); \
        __builtin_amdgcn_global_load_lds(                                       \
            (const __attribute__((address_space(1))) void*)(s_ + 4096 + tid * 8),\
            (__attribute__((address_space(3))) void*)(d_ + 4096 + tid * 8), 16, 0, 0); \
    }

    // prologue: issue chunks 0..2 (oldest in vmcnt FIFO)
    ISSUE(0, 0) ISSUE(1, 1) ISSUE(2, 2)

    // --- stage z tile: 64q x 256d fp32 -> hi/lo bf16, swizzled 16B units
    {
        const int rr = tid >> 6;          // 0..7 (one q row per wave per iter)
        const int c4 = (tid & 63) * 4;
        const int uh = c4 >> 3;
        const int ul = (256 + c4) >> 3;
        #pragma unroll
        for (int it = 0; it < 8; ++it) {
            const int q = it * 8 + rr;
            const float4 v = *reinterpret_cast<const float4*>(
                &z[(size_t)(q0 + q) * ND + c4]);
            const float xs[4] = {v.x, v.y, v.z, v.w};
            ushort4 h4, l4;
            ushort* hp = &h4.x; ushort* lp = &l4.x;
            #pragma unroll
            for (int j = 0; j < 4; ++j) {
                const ushort h = bf_trunc(xs[j]);
                hp[j] = h;
                lp[j] = bf_trunc(xs[j] - bf_back(h));
            }
            const int sw = q & 7;
            *reinterpret_cast<ushort4*>(&zt[q][((uh ^ sw) << 3) + (c4 & 7)]) = h4;
            *reinterpret_cast<ushort4*>(&zt[q][((ul ^ sw) << 3) + (c4 & 7)]) = l4;
        }
    }
    #pragma unroll
    for (int i = 0; i < 2; ++i)
        csq_l[i * 512 + tid] = (float)csqd[i * 512 + tid];

    asm volatile("s_waitcnt lgkmcnt(0)" ::: "memory");
    __builtin_amdgcn_s_barrier();
    __builtin_amdgcn_sched_barrier(0);

    float b1[8], b2[8]; int bidx[8];
    #pragma unroll
    for (int s = 0; s < 8; ++s) { b1[s] = 3.0e38f; b2[s] = 3.0e38f; bidx[s] = 0; }

    const int kq8 = (lane >> 4) * 8;      // k-octet (8 bf16 = one 16B unit)
    const int cl  = lane & 15;

    int step = 0;
    #pragma unroll 1
    for (int ct = 0; ct < 4; ++ct) {
        f32x4 acc[2][4];
        #pragma unroll
        for (int mi = 0; mi < 2; ++mi)
            #pragma unroll
            for (int ni = 0; ni < 4; ++ni)
                acc[mi][ni] = (f32x4){0.f, 0.f, 0.f, 0.f};

        #pragma unroll 1
        for (int kc = 0; kc < 16; ++kc, ++step) {
            // counted wait: chunk `step` landed; chunks step+1..step+2 stay in flight
            if (step < 62)       asm volatile("s_waitcnt vmcnt(4)" ::: "memory");
            else if (step == 62) asm volatile("s_waitcnt vmcnt(2)" ::: "memory");
            else                 asm volatile("s_waitcnt vmcnt(0)" ::: "memory");
            __builtin_amdgcn_s_barrier();
            __builtin_amdgcn_sched_barrier(0);
            // issue chunk step+3 into slot (step-1)&3 (all waves done reading it)
            if (step + 3 < 64) ISSUE(step + 3, (step + 3) & 3)

            const ushort* ch = &ring[step & 3][0][0];

            bf16x8 bfr[4];
            #pragma unroll
            for (int ni = 0; ni < 4; ++ni) {
                const int c = wx * 64 + ni * 16 + cl;
                const int u = (kq8 >> 3) ^ (c & 3);
                bfr[ni] = *reinterpret_cast<const bf16x8*>(ch + c * 32 + (u << 3));
            }
            const int zb = (kc < 8 ? kc : kc - 8) * 32;

            bf16x8 afr[2];
            #pragma unroll
            for (int mi = 0; mi < 2; ++mi) {
                const int q  = wy * 32 + mi * 16 + cl;
                const int uc = ((zb + kq8) >> 3) ^ (q & 7);
                afr[mi] = *reinterpret_cast<const bf16x8*>(&zt[q][uc << 3]);
            }
            __builtin_amdgcn_s_setprio(1);
            #pragma unroll
            for (int mi = 0; mi < 2; ++mi)
                #pragma unroll
                for (int ni = 0; ni < 4; ++ni)
                    acc[mi][ni] = __builtin_amdgcn_mfma_f32_16x16x32_bf16(
                        afr[mi], bfr[ni], acc[mi][ni], 0, 0, 0);
            __builtin_amdgcn_s_setprio(0);

            if (kc < 8) {   // c_hi chunk also pairs with z_lo
                bf16x8 afl[2];
                #pragma unroll
                for (int mi = 0; mi < 2; ++mi) {
                    const int q  = wy * 32 + mi * 16 + cl;
                    const int uc = ((256 + zb + kq8) >> 3) ^ (q & 7);
                    afl[mi] = *reinterpret_cast<const bf16x8*>(&zt[q][uc << 3]);
                }
                __builtin_amdgcn_s_setprio(1);
                #pragma unroll
                for (int mi = 0; mi < 2; ++mi)
                    #pragma unroll
                    for (int ni = 0; ni < 4; ++ni)
                        acc[mi][ni] = __builtin_amdgcn_mfma_f32_16x16x32_bf16(
                            afl[mi], bfr[ni], acc[mi][ni], 0, 0, 0);
                __builtin_amdgcn_s_setprio(0);
            }
        }

        // fold this code-tile into the running top-2 (register-only + csq_l)
        #pragma unroll
        for (int ni = 0; ni < 4; ++ni) {
            const int code = ct * 256 + wx * 64 + ni * 16 + cl;
            const float cs = csq_l[code];
            #pragma unroll
            for (int mi = 0; mi < 2; ++mi)
                #pragma unroll
                for (int r = 0; r < 4; ++r) {
                    const float d = fmaf(-2.0f, acc[mi][ni][r], cs);
                    const int s = mi * 4 + r;
                    if (d < b1[s]) { b2[s] = b1[s]; b1[s] = d; bidx[s] = code; }
                    else if (d < b2[s]) b2[s] = d;
                }
        }
    }

    // --- cross-lane top-2 reduce within each 16-lane column group
    #pragma unroll
    for (int s = 0; s < 8; ++s) {
        float B1 = b1[s], B2 = b2[s]; int BI = bidx[s];
        #pragma unroll
        for (int m = 1; m < 16; m <<= 1) {
            const float o1 = __shfl_xor(B1, m);
            const float o2 = __shfl_xor(B2, m);
            const int   oi = __shfl_xor(BI, m);
            const float n2 = fminf(fmaxf(B1, o1), fminf(B2, o2));
            const bool sel = (o1 < B1) || (o1 == B1 && oi < BI);
            B1 = fminf(B1, o1); BI = sel ? oi : BI; B2 = n2;
        }
        if (cl == 0) {
            const int mi = s >> 2, r = s & 3;
            const int q = wy * 32 + mi * 16 + (lane >> 4) * 4 + r;
            wb1[wx][q] = B1; wb2[wx][q] = B2; wbi[wx][q] = BI;
        }
    }
    __syncthreads();

    // --- combine 4 code-quarter candidates, flag tight margins
    if (tid < 64) {
        float B1 = wb1[0][tid], B2 = wb2[0][tid]; int BI = wbi[0][tid];
        #pragma unroll
        for (int ww = 1; ww < 4; ++ww) {
            const float o1 = wb1[ww][tid], o2 = wb2[ww][tid];
            const int   oi = wbi[ww][tid];
            const float n2 = fminf(fmaxf(B1, o1), fminf(B2, o2));
            const bool sel = (o1 < B1) || (o1 == B1 && oi < BI);
            B1 = fminf(B1, o1); BI = sel ? oi : BI; B2 = n2;
        }
        qidx[tid] = BI;
        if (B2 - B1 < TAU) {
            const int pos = atomicAdd(cnt, 1);
            lst[pos] = q0 + tid;
        }
    }
    __syncthreads();

    // --- gather: out[q][:] = cb[idx[q]][:]
    {
        const int rr = tid >> 6;
        const int c  = (tid & 63) * 4;
        #pragma unroll
        for (int it = 0; it < 8; ++it) {
            const int q = it * 8 + rr;
            const int k = qidx[q];
            *reinterpret_cast<float4*>(&out[(size_t)(q0 + q) * ND + c]) =
                *reinterpret_cast<const float4*>(&cb[(size_t)k * ND + c]);
        }
    }
#undef ISSUE
}

// --------------------------------------------------------------- fixup ----
// Exact fp64 re-solve for flagged (tight-margin) queries.
__global__ __launch_bounds__(256, 1)
void vq_fix(const float* __restrict__ z, const float* __restrict__ cb,
            uint8_t* __restrict__ ws, float* __restrict__ out)
{
    __shared__ double zd[ND];
    __shared__ double rb[256];
    __shared__ int    ri[256];

    const int* cnt = (const int*)(ws + WS_CNT);
    const int* lst = (const int*)(ws + WS_LST);
    const int tid = threadIdx.x;
    const int n = *cnt;

    for (int i = blockIdx.x; i < n; i += gridDim.x) {
        const int q = lst[i];
        __syncthreads();
        zd[tid] = (double)z[(size_t)q * ND + tid];
        __syncthreads();

        double best = 1.0e300; int bi = 0;
        #pragma unroll 1
        for (int j = 0; j < 4; ++j) {
            const int k = tid * 4 + j;
            double s = 0.0;
            const float* row = &cb[(size_t)k * ND];
            for (int d = 0; d < ND; ++d) {
                const double df = zd[d] - (double)row[d];
                s = fma(df, df, s);
            }
            if (s < best) { best = s; bi = k; }
        }
        rb[tid] = best; ri[tid] = bi;
        __syncthreads();
        for (int m = 128; m > 0; m >>= 1) {
            if (tid < m) {
                if (rb[tid + m] < rb[tid] ||
                    (rb[tid + m] == rb[tid] && ri[tid + m] < ri[tid])) {
                    rb[tid] = rb[tid + m]; ri[tid] = ri[tid + m];
                }
            }
            __syncthreads();
        }
        const int k = ri[0];
        if (tid < 64) {
            const float4 vv = *reinterpret_cast<const float4*>(
                &cb[(size_t)k * ND + tid * 4]);
            *reinterpret_cast<float4*>(&out[(size_t)q * ND + tid * 4]) = vv;
        }
        __syncthreads();
    }
}

// ------------------------------------------------- fallback (round-1) -----
// Verified-passing fp32 VALU kernel, used only if ws_size is insufficient.
__global__ __launch_bounds__(256, 2)
void vq_fallback(const float* __restrict__ z, const float* __restrict__ cb,
                 float* __restrict__ out)
{
    __shared__ float z_t[ND][64];
    __shared__ float cb_t[32][64];
    __shared__ float csq[NK];
    __shared__ int   idx_lds[64];

    const int tid = threadIdx.x;
    const int tx  = tid & 15;
    const int ty  = tid >> 4;
    const int q0  = blockIdx.x * 64;

    {
        const int r  = tid >> 6;
        const int c4 = (tid & 63) * 4;
        #pragma unroll
        for (int it = 0; it < 16; ++it) {
            const int q = it * 4 + r;
            const float4 v = *reinterpret_cast<const float4*>(
                &z[(size_t)(q0 + q) * ND + c4]);
            const float vv[4] = {v.x, v.y, v.z, v.w};
            #pragma unroll
            for (int j = 0; j < 4; ++j) {
                const int d = c4 + j;
                const int s = 4 * ((d >> 2) & 7);
                z_t[d][q ^ s] = vv[j];
            }
        }
    }
    {
        const int lane16 = tid & 15;
        const int rgrp   = tid >> 4;
        #pragma unroll 4
        for (int it = 0; it < 64; ++it) {
            const int k = it * 16 + rgrp;
            double ssum = 0.0;
            #pragma unroll
            for (int h = 0; h < 4; ++h) {
                const float4 v = *reinterpret_cast<const float4*>(
                    &cb[(size_t)k * ND + lane16 * 16 + h * 4]);
                ssum += (double)v.x * v.x + (double)v.y * v.y
                      + (double)v.z * v.z + (double)v.w * v.w;
            }
            #pragma unroll
            for (int m = 8; m >= 1; m >>= 1) ssum += __shfl_xor(ssum, m);
            if (lane16 == 0) csq[k] = (float)ssum;
        }
    }

    double bestd[4]; int besti[4];
    #pragma unroll
    for (int i = 0; i < 4; ++i) { bestd[i] = 1e300; besti[i] = 0; }

    for (int kt = 0; kt < 16; ++kt) {
        double acc[4][4];
        #pragma unroll
        for (int i = 0; i < 4; ++i)
            #pragma unroll
            for (int j = 0; j < 4; ++j) acc[i][j] = 0.0;

        for (int dc = 0; dc < 8; ++dc) {
            __syncthreads();
            {
                const int kk = tid >> 3;
                const int dd = (tid & 7) * 4;
                #pragma unroll
                for (int h = 0; h < 2; ++h) {
                    const int k = kk + h * 32;
                    const float4 v = *reinterpret_cast<const float4*>(
                        &cb[(size_t)(kt * 64 + k) * ND + dc * 32 + dd]);
                    const float vv[4] = {v.x, v.y, v.z, v.w};
                    #pragma unroll
                    for (int j = 0; j < 4; ++j) {
                        const int d = dd + j;
                        const int s = 4 * ((d >> 2) & 7);
                        cb_t[d][k ^ s] = vv[j];
                    }
                }
            }
            __syncthreads();

            float cr[4][4];
            #pragma unroll
            for (int i = 0; i < 4; ++i)
                #pragma unroll
                for (int j = 0; j < 4; ++j) cr[i][j] = 0.0f;

            #pragma unroll 8
            for (int d = 0; d < 32; ++d) {
                const int s  = 4 * ((d >> 2) & 7);
                const int dg = dc * 32 + d;
                const float4 zv4 = *reinterpret_cast<const float4*>(
                    &z_t[dg][(4 * ty) ^ s]);
                const float4 cv4 = *reinterpret_cast<const float4*>(
                    &cb_t[d][(4 * tx) ^ s]);
                const float zv[4] = {zv4.x, zv4.y, zv4.z, zv4.w};
                const float cv[4] = {cv4.x, cv4.y, cv4.z, cv4.w};
                #pragma unroll
                for (int i = 0; i < 4; ++i)
                    #pragma unroll
                    for (int j = 0; j < 4; ++j)
                        cr[i][j] = fmaf(zv[i], cv[j], cr[i][j]);
            }
            #pragma unroll
            for (int i = 0; i < 4; ++i)
                #pragma unroll
                for (int j = 0; j < 4; ++j)
                    acc[i][j] += (double)cr[i][j];
        }

        #pragma unroll
        for (int j = 0; j < 4; ++j) {
            const int k = kt * 64 + tx * 4 + j;
            const double cs = (double)csq[k];
            #pragma unroll
            for (int i = 0; i < 4; ++i) {
                const double dist = cs - 2.0 * acc[i][j];
                if (dist < bestd[i]) { bestd[i] = dist; besti[i] = k; }
            }
        }
    }

    #pragma unroll
    for (int i = 0; i < 4; ++i) {
        double bd = bestd[i]; int bi = besti[i];
        #pragma unroll
        for (int m = 8; m >= 1; m >>= 1) {
            const double od = __shfl_xor(bd, m);
            const int    oi = __shfl_xor(bi, m);
            if (od < bd || (od == bd && oi < bi)) { bd = od; bi = oi; }
        }
        if (tx == 0) idx_lds[ty * 4 + i] = bi;
    }
    __syncthreads();

    {
        const int r = tid >> 6;
        const int c = (tid & 63) * 4;
        #pragma unroll
        for (int it = 0; it < 16; ++it) {
            const int q = it * 4 + r;
            const int k = idx_lds[q];
            const float4 v = *reinterpret_cast<const float4*>(
                &cb[(size_t)k * ND + c]);
            *reinterpret_cast<float4*>(&out[(size_t)(q0 + q) * ND + c]) = v;
        }
    }
}

extern "C" void kernel_launch(void* const* d_in, const int* in_sizes, int n_in,
                              void* d_out, int out_size, void* d_ws, size_t ws_size,
                              hipStream_t stream)
{
    const float* z   = (const float*)d_in[0];   // [B,T,D] fp32
    const float* cbk = (const float*)d_in[1];   // [K,D]  fp32
    float* out = (float*)d_out;
    uint8_t* ws = (uint8_t*)d_ws;

    if (ws_size < (size_t)WS_NEEDED) {
        vq_fallback<<<NQ / 64, 256, 0, stream>>>(z, cbk, out);
        return;
    }

    vq_prep<<<NK, 64, 0, stream>>>(cbk, ws);
    vq_main<<<NQ / 64, 512, 0, stream>>>(z, cbk, ws, out);
    vq_fix<<<256, 256, 0, stream>>>(z, cbk, ws, out);
}

// Round 5
// 94.111 us; speedup vs baseline: 3.4650x; 1.8376x over previous
//
#include <hip/hip_runtime.h>
#include <stdint.h>

// VQ codebook assignment via split-precision bf16 MFMA:
//   argmin_k ||z-c_k||^2 == argmin_k (csq[k] - 2 z.c_k)
//   z.c ~= z_hi.c_hi + z_lo.c_hi + z_hi.c_lo   (bf16 hi/lo split, K_eff=768)
// Round-5 structure: NO LDS staging for the codebook — B frags load directly
// from the L2-resident 1MB cbw2 (coalesced per-quarter-wave). z tile in LDS
// (conflict-free XOR layout). Operand-swapped MFMA (D = codes x queries) so
// each lane's argmin candidates are register-local. No barriers in main loop;
// 2 blocks/CU (16 waves) for TLP. fp64 fixup for tight margins.

#define NQ 32768
#define ND 256
#define NK 1024
#define TAU 0.0078125f   // 2^-7 margin threshold for the exact-fixup path

typedef short bf16x8 __attribute__((ext_vector_type(8)));
typedef float f32x4  __attribute__((ext_vector_type(4)));

// ws layout (bytes); total ~1.19 MB
// cbw2: ushort [64 koct][1024 codes][8]; koct 0..31 = c_hi octet, 32..63 = c_lo
#define WS_CBW 0
#define WS_CSQ (64 * 1024 * 8 * 2)       // 1 MB; then double csq[1024]
#define WS_CNT (WS_CSQ + 1024 * 8)
#define WS_LST (WS_CNT + 16)
#define WS_NEEDED (WS_LST + NQ * 4)

__device__ __forceinline__ ushort bf_trunc(float x) {
    return (ushort)(__builtin_bit_cast(uint32_t, x) >> 16);
}
__device__ __forceinline__ float bf_back(ushort h) {
    return __builtin_bit_cast(float, ((uint32_t)h) << 16);
}

// ---------------------------------------------------------------- prep ----
// One block per code: hi/lo bf16 split into cbw2 (koct-major, coalesced for
// the main kernel's quarter-wave frag loads), csq in fp64.
__global__ __launch_bounds__(64)
void vq_prep(const float* __restrict__ cb, uint8_t* __restrict__ ws)
{
    ushort* cbw = (ushort*)(ws + WS_CBW);
    double* csq = (double*)(ws + WS_CSQ);
    int*    cnt = (int*)(ws + WS_CNT);

    const int code = blockIdx.x;
    const int lane = threadIdx.x;          // 0..63
    if (code == 0 && lane == 0) *cnt = 0;  // re-zero every launch (determinism)

    const int d0 = lane * 4;
    const float4 v = *reinterpret_cast<const float4*>(&cb[(size_t)code * ND + d0]);
    const float xs[4] = {v.x, v.y, v.z, v.w};

    ushort4 h4, l4;
    ushort* hp = &h4.x; ushort* lp = &l4.x;
    double ss = 0.0;
    #pragma unroll
    for (int j = 0; j < 4; ++j) {
        const ushort h = bf_trunc(xs[j]);
        hp[j] = h;
        lp[j] = bf_trunc(xs[j] - bf_back(h));
        ss += (double)xs[j] * (double)xs[j];
    }

    const int oct = d0 >> 3;             // 0..31
    const int off = d0 & 7;              // 0 or 4
    *reinterpret_cast<ushort4*>(&cbw[((size_t)oct * NK + code) * 8 + off]) = h4;
    *reinterpret_cast<ushort4*>(&cbw[((size_t)(32 + oct) * NK + code) * 8 + off]) = l4;

    #pragma unroll
    for (int m = 1; m < 64; m <<= 1) ss += __shfl_xor(ss, m);
    if (lane == 0) csq[code] = ss;
}

// ---------------------------------------------------------------- main ----
// 512 threads = 8 waves; block = 64 queries x 1024 codes (4 code-tiles).
// Wave tile: 64 q x 32 codes (cm=2 code sub-tiles x qt=4 query tiles).
__global__ __launch_bounds__(512, 4)
void vq_main(const float* __restrict__ z, const float* __restrict__ cb,
             uint8_t* __restrict__ ws, float* __restrict__ out)
{
    __shared__ ushort zt[64][512];        // z hi(units 0..31)|lo(32..63), XOR-swizzled
    __shared__ float  csq_l[NK];
    __shared__ float  wb1[8][64], wb2[8][64];
    __shared__ int    wbi[8][64];
    __shared__ int    qidx[64];

    const ushort* cbw  = (const ushort*)(ws + WS_CBW);
    const double* csqd = (const double*)(ws + WS_CSQ);
    int* cnt = (int*)(ws + WS_CNT);
    int* lst = (int*)(ws + WS_LST);

    const int tid  = threadIdx.x;
    const int lane = tid & 63;
    const int w    = tid >> 6;            // wave 0..7 -> 32-code slice per ct
    const int cl   = lane & 15;
    const int g    = lane >> 4;           // quarter 0..3 (k-octet / code-row group)
    const int q0   = blockIdx.x * 64;

    // --- stage z tile: 64q x 256d fp32 -> hi/lo bf16, swizzled 16B units
    {
        const int rr = tid >> 6;
        const int c4 = (tid & 63) * 4;
        const int uh = c4 >> 3;           // hi unit 0..31
        const int ul = (256 + c4) >> 3;   // lo unit 32..63
        #pragma unroll
        for (int it = 0; it < 8; ++it) {
            const int q = it * 8 + rr;
            const float4 v = *reinterpret_cast<const float4*>(
                &z[(size_t)(q0 + q) * ND + c4]);
            const float xs[4] = {v.x, v.y, v.z, v.w};
            ushort4 h4, l4;
            ushort* hp = &h4.x; ushort* lp = &l4.x;
            #pragma unroll
            for (int j = 0; j < 4; ++j) {
                const ushort h = bf_trunc(xs[j]);
                hp[j] = h;
                lp[j] = bf_trunc(xs[j] - bf_back(h));
            }
            const int sw = q & 7;
            *reinterpret_cast<ushort4*>(&zt[q][((uh ^ sw) << 3) + (c4 & 7)]) = h4;
            *reinterpret_cast<ushort4*>(&zt[q][((ul ^ sw) << 3) + (c4 & 7)]) = l4;
        }
    }
    #pragma unroll
    for (int i = 0; i < 2; ++i)
        csq_l[i * 512 + tid] = (float)csqd[i * 512 + tid];
    __syncthreads();

    // per-lane running top-2, one slot per q-tile (q = qt*16 + cl)
    float b1[4], b2[4]; int bidx[4];
    #pragma unroll
    for (int s = 0; s < 4; ++s) { b1[s] = 3.0e38f; b2[s] = 3.0e38f; bidx[s] = 0; }

    #pragma unroll 1
    for (int ct = 0; ct < 4; ++ct) {
        f32x4 acc[2][4];                  // [cm][qt]
        #pragma unroll
        for (int cm = 0; cm < 2; ++cm)
            #pragma unroll
            for (int qt = 0; qt < 4; ++qt)
                acc[cm][qt] = (f32x4){0.f, 0.f, 0.f, 0.f};

        const int cbase = ct * 256 + w * 32;

        #pragma unroll 1
        for (int kk = 0; kk < 8; ++kk) {
            // codebook frags (A-operand), direct from L2: hi & lo, 2 code rows
            bf16x8 cfh[2], cfl[2];
            #pragma unroll
            for (int cm = 0; cm < 2; ++cm) {
                const int code = cbase + cm * 16 + cl;
                const int oh   = kk * 4 + g;         // hi octet
                cfh[cm] = *reinterpret_cast<const bf16x8*>(
                    &cbw[((size_t)oh * NK + code) * 8]);
                cfl[cm] = *reinterpret_cast<const bf16x8*>(
                    &cbw[((size_t)(32 + oh) * NK + code) * 8]);
            }
            // z frags (B-operand) from LDS: hi & lo, 4 q-tiles
            bf16x8 zfh[4], zfl[4];
            #pragma unroll
            for (int qt = 0; qt < 4; ++qt) {
                const int q  = qt * 16 + cl;
                const int uh = (kk * 4 + g) ^ (q & 7);
                const int ul = (32 + kk * 4 + g) ^ (q & 7);
                zfh[qt] = *reinterpret_cast<const bf16x8*>(&zt[q][uh << 3]);
                zfl[qt] = *reinterpret_cast<const bf16x8*>(&zt[q][ul << 3]);
            }
            // 24 MFMA: hi*hi + hi*lo(z) + lo(c)*hi
            #pragma unroll
            for (int cm = 0; cm < 2; ++cm)
                #pragma unroll
                for (int qt = 0; qt < 4; ++qt) {
                    acc[cm][qt] = __builtin_amdgcn_mfma_f32_16x16x32_bf16(
                        cfh[cm], zfh[qt], acc[cm][qt], 0, 0, 0);
                    acc[cm][qt] = __builtin_amdgcn_mfma_f32_16x16x32_bf16(
                        cfh[cm], zfl[qt], acc[cm][qt], 0, 0, 0);
                    acc[cm][qt] = __builtin_amdgcn_mfma_f32_16x16x32_bf16(
                        cfl[cm], zfh[qt], acc[cm][qt], 0, 0, 0);
                }
        }

        // fold: lane holds, per qt, dists for codes cbase + cm*16 + g*4 + r
        #pragma unroll
        for (int cm = 0; cm < 2; ++cm) {
            const int kb = cbase + cm * 16 + g * 4;
            const float4 cs4 = *reinterpret_cast<const float4*>(&csq_l[kb]);
            const float css[4] = {cs4.x, cs4.y, cs4.z, cs4.w};
            #pragma unroll
            for (int qt = 0; qt < 4; ++qt)
                #pragma unroll
                for (int r = 0; r < 4; ++r) {
                    const float d = fmaf(-2.0f, acc[cm][qt][r], css[r]);
                    if (d < b1[qt]) { b2[qt] = b1[qt]; b1[qt] = d; bidx[qt] = kb + r; }
                    else if (d < b2[qt]) b2[qt] = d;
                }
        }
    }

    // --- combine the 4 quarters (same q = qt*16+cl, different codes)
    #pragma unroll
    for (int qt = 0; qt < 4; ++qt) {
        float B1 = b1[qt], B2 = b2[qt]; int BI = bidx[qt];
        #pragma unroll
        for (int m = 16; m < 64; m <<= 1) {
            const float o1 = __shfl_xor(B1, m);
            const float o2 = __shfl_xor(B2, m);
            const int   oi = __shfl_xor(BI, m);
            const float n2 = fminf(fmaxf(B1, o1), fminf(B2, o2));
            const bool sel = (o1 < B1) || (o1 == B1 && oi < BI);
            B1 = fminf(B1, o1); BI = sel ? oi : BI; B2 = n2;
        }
        if (g == 0) {
            const int q = qt * 16 + cl;
            wb1[w][q] = B1; wb2[w][q] = B2; wbi[w][q] = BI;
        }
    }
    __syncthreads();

    // --- combine 8 wave candidates, flag tight margins
    if (tid < 64) {
        float B1 = wb1[0][tid], B2 = wb2[0][tid]; int BI = wbi[0][tid];
        #pragma unroll
        for (int ww = 1; ww < 8; ++ww) {
            const float o1 = wb1[ww][tid], o2 = wb2[ww][tid];
            const int   oi = wbi[ww][tid];
            const float n2 = fminf(fmaxf(B1, o1), fminf(B2, o2));
            const bool sel = (o1 < B1) || (o1 == B1 && oi < BI);
            B1 = fminf(B1, o1); BI = sel ? oi : BI; B2 = n2;
        }
        qidx[tid] = BI;
        if (B2 - B1 < TAU) {
            const int pos = atomicAdd(cnt, 1);
            lst[pos] = q0 + tid;
        }
    }
    __syncthreads();

    // --- gather: out[q][:] = cb[idx[q]][:]
    {
        const int rr = tid >> 6;
        const int c  = (tid & 63) * 4;
        #pragma unroll
        for (int it = 0; it < 8; ++it) {
            const int q = it * 8 + rr;
            const int k = qidx[q];
            *reinterpret_cast<float4*>(&out[(size_t)(q0 + q) * ND + c]) =
                *reinterpret_cast<const float4*>(&cb[(size_t)k * ND + c]);
        }
    }
}

// --------------------------------------------------------------- fixup ----
// Exact fp64 re-solve for flagged (tight-margin) queries.
__global__ __launch_bounds__(256, 1)
void vq_fix(const float* __restrict__ z, const float* __restrict__ cb,
            uint8_t* __restrict__ ws, float* __restrict__ out)
{
    __shared__ double zd[ND];
    __shared__ double rb[256];
    __shared__ int    ri[256];

    const int* cnt = (const int*)(ws + WS_CNT);
    const int* lst = (const int*)(ws + WS_LST);
    const int tid = threadIdx.x;
    const int n = *cnt;

    for (int i = blockIdx.x; i < n; i += gridDim.x) {
        const int q = lst[i];
        __syncthreads();
        zd[tid] = (double)z[(size_t)q * ND + tid];
        __syncthreads();

        double best = 1.0e300; int bi = 0;
        #pragma unroll 1
        for (int j = 0; j < 4; ++j) {
            const int k = tid * 4 + j;
            double s = 0.0;
            const float* row = &cb[(size_t)k * ND];
            for (int d = 0; d < ND; ++d) {
                const double df = zd[d] - (double)row[d];
                s = fma(df, df, s);
            }
            if (s < best) { best = s; bi = k; }
        }
        rb[tid] = best; ri[tid] = bi;
        __syncthreads();
        for (int m = 128; m > 0; m >>= 1) {
            if (tid < m) {
                if (rb[tid + m] < rb[tid] ||
                    (rb[tid + m] == rb[tid] && ri[tid + m] < ri[tid])) {
                    rb[tid] = rb[tid + m]; ri[tid] = ri[tid + m];
                }
            }
            __syncthreads();
        }
        const int k = ri[0];
        if (tid < 64) {
            const float4 vv = *reinterpret_cast<const float4*>(
                &cb[(size_t)k * ND + tid * 4]);
            *reinterpret_cast<float4*>(&out[(size_t)q * ND + tid * 4]) = vv;
        }
        __syncthreads();
    }
}

// ------------------------------------------------- fallback (round-1) -----
// Verified-passing fp32 VALU kernel, used only if ws_size is insufficient.
__global__ __launch_bounds__(256, 2)
void vq_fallback(const float* __restrict__ z, const float* __restrict__ cb,
                 float* __restrict__ out)
{
    __shared__ float z_t[ND][64];
    __shared__ float cb_t[32][64];
    __shared__ float csq[NK];
    __shared__ int   idx_lds[64];

    const int tid = threadIdx.x;
    const int tx  = tid & 15;
    const int ty  = tid >> 4;
    const int q0  = blockIdx.x * 64;

    {
        const int r  = tid >> 6;
        const int c4 = (tid & 63) * 4;
        #pragma unroll
        for (int it = 0; it < 16; ++it) {
            const int q = it * 4 + r;
            const float4 v = *reinterpret_cast<const float4*>(
                &z[(size_t)(q0 + q) * ND + c4]);
            const float vv[4] = {v.x, v.y, v.z, v.w};
            #pragma unroll
            for (int j = 0; j < 4; ++j) {
                const int d = c4 + j;
                const int s = 4 * ((d >> 2) & 7);
                z_t[d][q ^ s] = vv[j];
            }
        }
    }
    {
        const int lane16 = tid & 15;
        const int rgrp   = tid >> 4;
        #pragma unroll 4
        for (int it = 0; it < 64; ++it) {
            const int k = it * 16 + rgrp;
            double ssum = 0.0;
            #pragma unroll
            for (int h = 0; h < 4; ++h) {
                const float4 v = *reinterpret_cast<const float4*>(
                    &cb[(size_t)k * ND + lane16 * 16 + h * 4]);
                ssum += (double)v.x * v.x + (double)v.y * v.y
                      + (double)v.z * v.z + (double)v.w * v.w;
            }
            #pragma unroll
            for (int m = 8; m >= 1; m >>= 1) ssum += __shfl_xor(ssum, m);
            if (lane16 == 0) csq[k] = (float)ssum;
        }
    }

    double bestd[4]; int besti[4];
    #pragma unroll
    for (int i = 0; i < 4; ++i) { bestd[i] = 1e300; besti[i] = 0; }

    for (int kt = 0; kt < 16; ++kt) {
        double acc[4][4];
        #pragma unroll
        for (int i = 0; i < 4; ++i)
            #pragma unroll
            for (int j = 0; j < 4; ++j) acc[i][j] = 0.0;

        for (int dc = 0; dc < 8; ++dc) {
            __syncthreads();
            {
                const int kk = tid >> 3;
                const int dd = (tid & 7) * 4;
                #pragma unroll
                for (int h = 0; h < 2; ++h) {
                    const int k = kk + h * 32;
                    const float4 v = *reinterpret_cast<const float4*>(
                        &cb[(size_t)(kt * 64 + k) * ND + dc * 32 + dd]);
                    const float vv[4] = {v.x, v.y, v.z, v.w};
                    #pragma unroll
                    for (int j = 0; j < 4; ++j) {
                        const int d = dd + j;
                        const int s = 4 * ((d >> 2) & 7);
                        cb_t[d][k ^ s] = vv[j];
                    }
                }
            }
            __syncthreads();

            float cr[4][4];
            #pragma unroll
            for (int i = 0; i < 4; ++i)
                #pragma unroll
                for (int j = 0; j < 4; ++j) cr[i][j] = 0.0f;

            #pragma unroll 8
            for (int d = 0; d < 32; ++d) {
                const int s  = 4 * ((d >> 2) & 7);
                const int dg = dc * 32 + d;
                const float4 zv4 = *reinterpret_cast<const float4*>(
                    &z_t[dg][(4 * ty) ^ s]);
                const float4 cv4 = *reinterpret_cast<const float4*>(
                    &cb_t[d][(4 * tx) ^ s]);
                const float zv[4] = {zv4.x, zv4.y, zv4.z, zv4.w};
                const float cv[4] = {cv4.x, cv4.y, cv4.z, cv4.w};
                #pragma unroll
                for (int i = 0; i < 4; ++i)
                    #pragma unroll
                    for (int j = 0; j < 4; ++j)
                        cr[i][j] = fmaf(zv[i], cv[j], cr[i][j]);
            }
            #pragma unroll
            for (int i = 0; i < 4; ++i)
                #pragma unroll
                for (int j = 0; j < 4; ++j)
                    acc[i][j] += (double)cr[i][j];
        }

        #pragma unroll
        for (int j = 0; j < 4; ++j) {
            const int k = kt * 64 + tx * 4 + j;
            const double cs = (double)csq[k];
            #pragma unroll
            for (int i = 0; i < 4; ++i) {
                const double dist = cs - 2.0 * acc[i][j];
                if (dist < bestd[i]) { bestd[i] = dist; besti[i] = k; }
            }
        }
    }

    #pragma unroll
    for (int i = 0; i < 4; ++i) {
        double bd = bestd[i]; int bi = besti[i];
        #pragma unroll
        for (int m = 8; m >= 1; m >>= 1) {
            const double od = __shfl_xor(bd, m);
            const int    oi = __shfl_xor(bi, m);
            if (od < bd || (od == bd && oi < bi)) { bd = od; bi = oi; }
        }
        if (tx == 0) idx_lds[ty * 4 + i] = bi;
    }
    __syncthreads();

    {
        const int r = tid >> 6;
        const int c = (tid & 63) * 4;
        #pragma unroll
        for (int it = 0; it < 16; ++it) {
            const int q = it * 4 + r;
            const int k = idx_lds[q];
            const float4 v = *reinterpret_cast<const float4*>(
                &cb[(size_t)k * ND + c]);
            *reinterpret_cast<float4*>(&out[(size_t)(q0 + q) * ND + c]) = v;
        }
    }
}

extern "C" void kernel_launch(void* const* d_in, const int* in_sizes, int n_in,
                              void* d_out, int out_size, void* d_ws, size_t ws_size,
                              hipStream_t stream)
{
    const float* z   = (const float*)d_in[0];   // [B,T,D] fp32
    const float* cbk = (const float*)d_in[1];   // [K,D]  fp32
    float* out = (float*)d_out;
    uint8_t* ws = (uint8_t*)d_ws;

    if (ws_size < (size_t)WS_NEEDED) {
        vq_fallback<<<NQ / 64, 256, 0, stream>>>(z, cbk, out);
        return;
    }

    vq_prep<<<NK, 64, 0, stream>>>(cbk, ws);
    vq_main<<<NQ / 64, 512, 0, stream>>>(z, cbk, ws, out);
    vq_fix<<<256, 256, 0, stream>>>(z, cbk, ws, out);
}